// Round 13
// baseline (310.509 us; speedup 1.0000x reference)
//
#include <hip/hip_runtime.h>
#include <hip/hip_bf16.h>

// NBFNet Bellman-Ford pass, MI355X. N=20000, E=200000, B=4, K=32, D=32, R=36, L=4.
// x layout: [n][d][b] (b innermost) -> gather reads one dwordx4 per edge per lane.
#define N_NODES 20000
#define N_EDGES 200000
#define BB 4
#define KK 32
#define DD 32
#define RR 36
#define LL 4
#define NCHUNKS (N_NODES / 16)   // 1250
#define NBLK 79                  // ceil(20000/256)

// ---------------- ws layout (element offsets, 4B units) ----------------
constexpr size_t OFF_X0   = 0;                                        // float[N*D*B], x[(n*32+d)*4+b]
constexpr size_t OFF_X1   = OFF_X0 + (size_t)BB * N_NODES * DD;
constexpr size_t OFF_RP   = OFF_X1 + (size_t)BB * N_NODES * DD;       // int[N+1]
constexpr size_t OFF_CUR  = OFF_RP + 20032;                           // int[N]
constexpr size_t OFF_ES   = OFF_CUR + N_NODES;                        // int[E] src | type<<16
constexpr size_t OFF_DEG  = OFF_ES + N_EDGES;                         // float[N] 1/deg
constexpr size_t OFF_SC   = OFF_DEG + N_NODES;                        // float[N] scale
constexpr size_t OFF_INV  = OFF_SC + N_NODES;                         // float[N] 1/max(scale,.01)
constexpr size_t OFF_BS   = OFF_INV + N_NODES;                        // int[128] block sums
constexpr size_t OFF_BL   = OFF_BS + 128;                             // float[128] block log sums
constexpr size_t OFF_BO   = OFF_BL + 128;                             // int[128] block offsets
constexpr size_t OFF_MEAN = OFF_BO + 128;                             // float[16]
constexpr size_t OFF_REL  = OFF_MEAN + 16;                            // float[L*R*D*B] [l][ty][d][b]
constexpr size_t OFF_PW   = OFF_REL + (size_t)LL * RR * BB * DD;      // float[L*4*3328]

// ---------------- prep kernels ----------------

__global__ void k_init(const int* __restrict__ h_index, const int* __restrict__ r_index,
                       const float* __restrict__ query_emb, float* __restrict__ x0,
                       int* __restrict__ cursor) {
    int i = blockIdx.x * blockDim.x + threadIdx.x;
    int stride = gridDim.x * blockDim.x;
    for (int t = i; t < N_NODES; t += stride) cursor[t] = 0;
    for (int t = i; t < BB * N_NODES * DD; t += stride) {
        int b = t & 3; int d = (t >> 2) & 31; int n = t >> 7;
        float v = 0.f;
        if (n == h_index[b]) v = query_emb[r_index[b] * DD + d];
        x0[t] = v;
    }
}

__global__ void k_hist(const int* __restrict__ ei, int* __restrict__ cursor) {
    int e = blockIdx.x * blockDim.x + threadIdx.x;
    if (e < N_EDGES) atomicAdd(&cursor[ei[N_EDGES + e]], 1);
}

// per-block partial sums of deg histogram + log(deg)
__global__ void k_part(const int* __restrict__ cursor, int* __restrict__ bsum,
                       float* __restrict__ blog) {
    __shared__ int si[256];
    __shared__ float sf2[256];
    int tid = threadIdx.x;
    int i = blockIdx.x * 256 + tid;
    int v = (i < N_NODES) ? cursor[i] : 0;
    float lg = (i < N_NODES) ? logf((float)(v + 1)) : 0.f;
    si[tid] = v; sf2[tid] = lg;
    __syncthreads();
    for (int off = 128; off > 0; off >>= 1) {
        if (tid < off) { si[tid] += si[tid + off]; sf2[tid] += sf2[tid + off]; }
        __syncthreads();
    }
    if (tid == 0) { bsum[blockIdx.x] = si[0]; blog[blockIdx.x] = sf2[0]; }
}

// single small block: scan the 79 block sums; total log -> mean
__global__ void k_scan2(const int* __restrict__ bsum, const float* __restrict__ blog,
                        int* __restrict__ boff, float* __restrict__ meanw) {
    __shared__ int si[128];
    __shared__ float sf2[128];
    int t = threadIdx.x;
    int v = (t < NBLK) ? bsum[t] : 0;
    float lg = (t < NBLK) ? blog[t] : 0.f;
    si[t] = v; sf2[t] = lg;
    __syncthreads();
    for (int off = 1; off < 128; off <<= 1) {
        int tv = (t >= off) ? si[t - off] : 0;
        float tf = (t >= off) ? sf2[t - off] : 0.f;
        __syncthreads();
        si[t] += tv; sf2[t] += tf;
        __syncthreads();
    }
    if (t < NBLK) boff[t] = si[t] - v;                      // exclusive
    if (t == 127) meanw[0] = sf2[127] / (float)N_NODES;     // mean(log deg)
}

// per-block scan + global offset -> row_ptr/cursor; rdeg/scale/inv
__global__ void k_final(int* __restrict__ cursor, int* __restrict__ row_ptr,
                        const int* __restrict__ boff, const float* __restrict__ meanw,
                        float* __restrict__ rdeg, float* __restrict__ scale,
                        float* __restrict__ invs) {
    __shared__ int si[256];
    int tid = threadIdx.x;
    int i = blockIdx.x * 256 + tid;
    int v = (i < N_NODES) ? cursor[i] : 0;
    si[tid] = v;
    __syncthreads();
    for (int off = 1; off < 256; off <<= 1) {
        int tv = (tid >= off) ? si[tid - off] : 0;
        __syncthreads();
        si[tid] += tv;
        __syncthreads();
    }
    int rp = boff[blockIdx.x] + si[tid] - v;   // exclusive prefix
    if (i < N_NODES) {
        row_ptr[i] = rp;
        cursor[i] = rp;
        float dg = (float)(v + 1);
        float sc = logf(dg) / meanw[0];
        rdeg[i] = 1.f / dg;
        scale[i] = sc;
        invs[i] = 1.f / fmaxf(sc, 0.01f);
    }
    if (i == 0) row_ptr[N_NODES] = N_EDGES;
}

__global__ void k_scatter(const int* __restrict__ ei, const int* __restrict__ et,
                          int* __restrict__ cursor, int* __restrict__ es) {
    int e = blockIdx.x * blockDim.x + threadIdx.x;
    if (e < N_EDGES) {
        int dnode = ei[N_EDGES + e];
        int p = atomicAdd(&cursor[dnode], 1);
        es[p] = ei[e] | (et[e] << 16);
    }
}

// rel tables [l][ty][d][b] + prepped conv weights.
// pw layout per (l, og), og in [0,4) covering outputs o = og*8 .. og*8+7 (3328 floats):
//   r in [0,256):   x-part.  j = r>>3, o = og*8 + (r&7)
//   r in [256,3328): feats.  r2=r-256; jj=r2/96; rem=r2%96; pf=rem>>3 (= f*3+k);
//                   o = og*8 + (rem&7); col = 32 + (jj*4 + pf/3)*3 + pf%3
__global__ void k_prep_w(const float* __restrict__ query_emb, const int* __restrict__ r_index,
                         const float* __restrict__ rel_W, const float* __restrict__ rel_b,
                         const float* __restrict__ conv_W,
                         float* __restrict__ rel_all, float* __restrict__ pw) {
    int i = blockIdx.x * blockDim.x + threadIdx.x;
    const int NREL = LL * BB * RR * DD;
    if (i < NREL) {
        int d = i & 31;
        int ty = (i >> 5) % RR;
        int b = (i / (32 * RR)) & 3;
        int l = i / (32 * RR * BB);
        const float* q = query_emb + r_index[b] * DD;
        const float* w = rel_W + ((size_t)l * RR * DD + ty * DD + d) * DD;
        float acc = rel_b[l * RR * DD + ty * DD + d];
        #pragma unroll
        for (int k2 = 0; k2 < DD; ++k2) acc = fmaf(q[k2], w[k2], acc);
        rel_all[(((size_t)l * RR + ty) * DD + d) * BB + b] = acc;
    } else {
        int i2 = i - NREL;
        if (i2 >= LL * 4 * 3328) return;
        int r = i2 % 3328; int lg2 = i2 / 3328;
        int og = lg2 & 3, l = lg2 >> 2;
        int o, col;
        if (r < 256) { col = r >> 3; o = og * 8 + (r & 7); }
        else {
            int r2 = r - 256;
            int jj = r2 / 96, rem = r2 % 96;
            int pf = rem >> 3;
            o = og * 8 + (rem & 7);
            col = DD + (jj * 4 + pf / 3) * 3 + (pf % 3);
        }
        pw[i2] = conv_W[(size_t)(l * DD + o) * (13 * DD) + col];
    }
}

// ---------------- fused layer kernel ----------------
// One chunk (16 nodes x 4 b = 64 tasks) per 256-thr block; grid = 1250.
// Phase A (gather): wave wv handles nodes wv*4..wv*4+3; lane = d + 32*par;
//   parity halves alternate edges (4-deep unroll, 8 dwordx4 in flight);
//   shfl_xor(32) combine; stats -> LDS s_F[task][d ^ (task&7)] (XOR swizzle:
//   [d][task] layout would be a 32-way ds_write conflict; [task][d] unswizzled
//   a 64-way ds_read conflict in phase B).
// Phase B (conv): wave wv = out-group of 8 outputs; lane = task; F from LDS;
//   weights on the scalar path (uniform base + compile-time offsets -> s_load,
//   K$/L2-hot; fixed since r10 -- this was r1-r3's fusion killer).
// Fusion kills the Fq round-trip (41 MB write + read per layer) and one launch
// per layer; A-latency of one block overlaps B-FMAs of CU-neighbors (3 blk/CU).
__launch_bounds__(256, 3)
__global__ void k_layer(const float* __restrict__ xin, float* __restrict__ xout,
                        const int* __restrict__ row_ptr, const int* __restrict__ es,
                        const float* __restrict__ rel_l, const float* __restrict__ pw_l,
                        const float* __restrict__ rdeg, const float* __restrict__ scale,
                        const float* __restrict__ invs,
                        const int* __restrict__ h_index, const int* __restrict__ r_index,
                        const float* __restrict__ query_emb, const float* __restrict__ conv_b_l) {
    __shared__ __align__(16) float s_rel[RR * BB * DD];   // 18432 B, [ty][d][b]
    __shared__ __align__(16) float4 s_F[64 * 32];         // 32768 B, [task][d ^ (task&7)]
    const int tid = threadIdx.x;
    {   // stage rel table once per block
        const float4* p4 = (const float4*)rel_l;
        float4* s4 = (float4*)s_rel;
        for (int i = tid; i < RR * BB * DD / 4; i += 256) s4[i] = p4[i];
    }
    const int wv = tid >> 6;
    const int lane = tid & 63;
    const int d = lane & 31;
    const int par = lane >> 5;
    const int chunk = blockIdx.x;
    int hb[4]; float qv[4];
    #pragma unroll
    for (int b = 0; b < 4; ++b) {
        hb[b] = h_index[b];
        qv[b] = query_emb[r_index[b] * DD + d];
    }
    __syncthreads();

    // ---------- Phase A: gather + PNA ----------
    #pragma unroll 1
    for (int i4 = 0; i4 < 4; ++i4) {
        const int nl = wv * 4 + i4;
        const int n = chunk * 16 + nl;
        float sa[4], sq[4], mx[4], mn[4];
        #pragma unroll
        for (int b = 0; b < 4; ++b) {
            float bv = (n == hb[b]) ? qv[b] : 0.f;
            float bs = par ? 0.f : bv;        // count boundary message once in sum/sq
            sa[b] = bs; sq[b] = bs * bv; mx[b] = bv; mn[b] = bv;
        }
        auto proc = [&](int ee) {
            int pk = es[ee];
            float4 xv = *(const float4*)(xin + ((size_t)(pk & 0xFFFF) * DD + d) * 4);
            float4 rv = *(const float4*)(s_rel + (((pk >> 16) * DD) + d) * 4);
            #pragma unroll
            for (int b = 0; b < 4; ++b) {
                float m = (&xv.x)[b] * (&rv.x)[b];
                sa[b] += m; sq[b] = fmaf(m, m, sq[b]);
                mx[b] = fmaxf(mx[b], m); mn[b] = fminf(mn[b], m);
            }
        };
        int e0 = row_ptr[n], e1 = row_ptr[n + 1];
        int e = e0 + par;                        // parity-strided: 2 edges per step
        for (; e + 6 < e1; e += 8) { proc(e); proc(e + 2); proc(e + 4); proc(e + 6); }
        for (; e < e1; e += 2) proc(e);
        #pragma unroll
        for (int b = 0; b < 4; ++b) {
            sa[b] += __shfl_xor(sa[b], 32);
            sq[b] += __shfl_xor(sq[b], 32);
            mx[b] = fmaxf(mx[b], __shfl_xor(mx[b], 32));
            mn[b] = fminf(mn[b], __shfl_xor(mn[b], 32));
        }
        float rd_ = rdeg[n];
        float mean[4], sd[4];
        #pragma unroll
        for (int b = 0; b < 4; ++b) {
            mean[b] = sa[b] * rd_;
            float sm = sq[b] * rd_;
            sd[b] = sqrtf(fmaxf(sm - mean[b] * mean[b], 1e-6f));
        }
        int tA = nl * 4 + par * 2;               // each half writes 2 tasks
        float4 fA, fB;
        fA.x = par ? mean[2] : mean[0]; fA.y = par ? mx[2] : mx[0];
        fA.z = par ? mn[2] : mn[0];     fA.w = par ? sd[2] : sd[0];
        fB.x = par ? mean[3] : mean[1]; fB.y = par ? mx[3] : mx[1];
        fB.z = par ? mn[3] : mn[1];     fB.w = par ? sd[3] : sd[1];
        s_F[tA * 32 + (d ^ (tA & 7))] = fA;
        s_F[(tA + 1) * 32 + (d ^ ((tA + 1) & 7))] = fB;
    }
    __syncthreads();

    // ---------- Phase B: conv ----------
    {
        const int og = __builtin_amdgcn_readfirstlane(wv);   // 0..3, SGPR
        const float* wxp = pw_l + og * 3328;      // x weights [32 j][8 o], uniform
        const float* wfp = wxp + 256;             // feat weights [32 jj][12 pf][8 o], uniform
        const int nl2 = lane >> 2, b2 = lane & 3;
        const int n = chunk * 16 + nl2;
        const int sw = lane & 7;

        float y0[8], y1[8], y2[8];
        #pragma unroll
        for (int oo = 0; oo < 8; ++oo) {
            y0[oo] = conv_b_l[og * 8 + oo];
            y1[oo] = 0.f;
            y2[oo] = 0.f;
        }

        // x part: 32 K-rows ([n][d][b] layout, L1/L2-hot)
        const float* xb = xin + (size_t)n * 128 + b2;
        #pragma unroll 2
        for (int jg = 0; jg < 8; ++jg) {
            float cxv[4];
            #pragma unroll
            for (int dj = 0; dj < 4; ++dj) cxv[dj] = xb[(jg * 4 + dj) * 4];
            #pragma unroll
            for (int dj = 0; dj < 4; ++dj) {
                const float* wp = wxp + (jg * 4 + dj) * 8;
                #pragma unroll
                for (int oo = 0; oo < 8; ++oo) y0[oo] = fmaf(cxv[dj], wp[oo], y0[oo]);
            }
        }

        // feats: 32 d-rows from LDS (swizzled), f = mean/max/min/std
        #pragma unroll 1
        for (int jj = 0; jj < 32; ++jj) {
            float4 cf = s_F[lane * 32 + (jj ^ sw)];
            const float* wp = wfp + jj * 96;
            #pragma unroll
            for (int f = 0; f < 4; ++f) {
                float cv = (&cf.x)[f];
                const float* w8 = wp + f * 24;    // pf = f*3+k -> f*24 + k*8 + o
                #pragma unroll
                for (int oo = 0; oo < 8; ++oo) y0[oo] = fmaf(cv, w8[oo], y0[oo]);
                #pragma unroll
                for (int oo = 0; oo < 8; ++oo) y1[oo] = fmaf(cv, w8[8 + oo], y1[oo]);
                #pragma unroll
                for (int oo = 0; oo < 8; ++oo) y2[oo] = fmaf(cv, w8[16 + oo], y2[oo]);
            }
        }

        // epilogue: out[n][o][b] scalar stores
        float scn = scale[n], ivn = invs[n];
        float* xo = xout + (size_t)n * 128 + b2;
        #pragma unroll
        for (int oo = 0; oo < 8; ++oo) {
            float v = fmaxf(0.f, y0[oo] + scn * y1[oo] + ivn * y2[oo]);
            xo[(og * 8 + oo) * 4] = v;
        }
    }
}

// ---------------- final scoring ----------------
__global__ void k_score(const float* __restrict__ xL, const float* __restrict__ query_emb,
                        const int* __restrict__ r_index, const int* __restrict__ t_index,
                        const float* __restrict__ W1, const float* __restrict__ b1,
                        const float* __restrict__ W2, const float* __restrict__ b2,
                        float* __restrict__ out) {
    int bi = blockIdx.x;            // 0..127
    int b = bi >> 5, kk = bi & 31;
    int j = threadIdx.x;            // 0..63
    __shared__ float sf[64];
    int t = t_index[b * KK + kk];
    float f = (j < DD) ? xL[(size_t)t * 128 + j * 4 + b]
                       : query_emb[r_index[b] * DD + (j - DD)];
    sf[j] = f;
    __syncthreads();
    float acc = b1[j];
    #pragma unroll 8
    for (int i2 = 0; i2 < 64; ++i2) acc = fmaf(sf[i2], W1[j * 64 + i2], acc);
    float h = fmaxf(acc, 0.f);
    float prod = h * W2[j];
    #pragma unroll
    for (int off = 32; off > 0; off >>= 1) prod += __shfl_down(prod, off);
    if (j == 0) out[b * KK + kk] = prod + b2[0];
}

extern "C" void kernel_launch(void* const* d_in, const int* in_sizes, int n_in,
                              void* d_out, int out_size, void* d_ws, size_t ws_size,
                              hipStream_t stream) {
    const int* ei        = (const int*)d_in[0];
    const int* et        = (const int*)d_in[1];
    const int* h_index   = (const int*)d_in[2];
    const int* t_index   = (const int*)d_in[3];
    const int* r_index   = (const int*)d_in[4];
    const float* query_emb = (const float*)d_in[6];
    const float* rel_W   = (const float*)d_in[7];
    const float* rel_b   = (const float*)d_in[8];
    const float* conv_W  = (const float*)d_in[9];
    const float* conv_b  = (const float*)d_in[10];
    const float* W1      = (const float*)d_in[11];
    const float* b1      = (const float*)d_in[12];
    const float* W2      = (const float*)d_in[13];
    const float* b2      = (const float*)d_in[14];

    float* ws = (float*)d_ws;
    float* x0      = ws + OFF_X0;
    float* x1      = ws + OFF_X1;
    int*   row_ptr = (int*)(ws + OFF_RP);
    int*   cursor  = (int*)(ws + OFF_CUR);
    int*   es      = (int*)(ws + OFF_ES);
    float* rdeg    = ws + OFF_DEG;
    float* sc      = ws + OFF_SC;
    float* invs    = ws + OFF_INV;
    int*   bsum    = (int*)(ws + OFF_BS);
    float* blog    = ws + OFF_BL;
    int*   boff    = (int*)(ws + OFF_BO);
    float* meanw   = ws + OFF_MEAN;
    float* rel_all = ws + OFF_REL;
    float* pw      = ws + OFF_PW;
    float* out     = (float*)d_out;

    // prep
    k_init<<<1024, 256, 0, stream>>>(h_index, r_index, query_emb, x0, cursor);
    k_hist<<<(N_EDGES + 255) / 256, 256, 0, stream>>>(ei, cursor);
    k_part<<<NBLK, 256, 0, stream>>>(cursor, bsum, blog);
    k_scan2<<<1, 128, 0, stream>>>(bsum, blog, boff, meanw);
    k_final<<<NBLK, 256, 0, stream>>>(cursor, row_ptr, boff, meanw, rdeg, sc, invs);
    k_scatter<<<(N_EDGES + 255) / 256, 256, 0, stream>>>(ei, et, cursor, es);
    const int NPREP = LL * BB * RR * DD + LL * 4 * 3328;
    k_prep_w<<<(NPREP + 255) / 256, 256, 0, stream>>>(query_emb, r_index, rel_W, rel_b,
                                                      conv_W, rel_all, pw);

    // 4 fused BF layers, ping-pong x0/x1
    for (int l = 0; l < LL; ++l) {
        const float* xi = (l & 1) ? x1 : x0;
        float* xo = (l & 1) ? x0 : x1;
        k_layer<<<NCHUNKS, 256, 0, stream>>>(xi, xo, row_ptr, es,
                                             rel_all + (size_t)l * RR * BB * DD,
                                             pw + (size_t)l * 4 * 3328,
                                             rdeg, sc, invs, h_index, r_index,
                                             query_emb, conv_b + l * DD);
    }

    k_score<<<BB * KK, 64, 0, stream>>>(x0, query_emb, r_index, t_index, W1, b1, W2, b2, out);
}

// Round 14
// 284.589 us; speedup vs baseline: 1.0911x; 1.0911x over previous
//
#include <hip/hip_runtime.h>
#include <hip/hip_bf16.h>

// NBFNet Bellman-Ford pass, MI355X. N=20000, E=200000, B=4, K=32, D=32, R=36, L=4.
// x kept in TWO layouts: A = [n][d][b] (gather's 1KB-per-edge coalesced reads),
// B = [n][b][d] (conv x-part float4 reads + coalesced epilogue stores).
#define N_NODES 20000
#define N_EDGES 200000
#define BB 4
#define KK 32
#define DD 32
#define RR 36
#define LL 4
#define NCHUNKS (N_NODES / 16)   // 1250
#define NBLK 79                  // ceil(20000/256)
#define NXD ((size_t)BB * N_NODES * DD)   // 2,560,000 floats per x copy

// ---------------- ws layout (element offsets, 4B units) ----------------
constexpr size_t OFF_X0A  = 0;                                        // float[N*D*B] layout A
constexpr size_t OFF_X1A  = OFF_X0A + NXD;
constexpr size_t OFF_X0B  = OFF_X1A + NXD;                            // float[N*B*D] layout B
constexpr size_t OFF_X1B  = OFF_X0B + NXD;
constexpr size_t OFF_RP   = OFF_X1B + NXD;                            // int[N+1]
constexpr size_t OFF_CUR  = OFF_RP + 20032;                           // int[N]
constexpr size_t OFF_ES   = OFF_CUR + N_NODES;                        // int[E] src | type<<16
constexpr size_t OFF_DEG  = OFF_ES + N_EDGES;                         // float[N] 1/deg
constexpr size_t OFF_SC   = OFF_DEG + N_NODES;                        // float[N] scale
constexpr size_t OFF_INV  = OFF_SC + N_NODES;                         // float[N] 1/max(scale,.01)
constexpr size_t OFF_BS   = OFF_INV + N_NODES;                        // int[128] block sums
constexpr size_t OFF_BL   = OFF_BS + 128;                             // float[128] block log sums
constexpr size_t OFF_BO   = OFF_BL + 128;                             // int[128] block offsets
constexpr size_t OFF_MEAN = OFF_BO + 128;                             // float[16]
constexpr size_t OFF_REL  = OFF_MEAN + 16;                            // float[L*R*D*B] [l][ty][d][b]
constexpr size_t OFF_PW   = OFF_REL + (size_t)LL * RR * BB * DD;      // float[L*4*3328]
constexpr size_t OFF_F    = OFF_PW + (size_t)LL * 4 * 3328;           // float4[(NCHUNKS*32+64)*64]
// Fq keeps 64 rows of slack: the ping-pong prefetch reads 1 row past each chunk.

// ---------------- prep kernels ----------------

__global__ void k_init(const int* __restrict__ h_index, const int* __restrict__ r_index,
                       const float* __restrict__ query_emb, float* __restrict__ x0a,
                       float* __restrict__ x0b, int* __restrict__ cursor) {
    int i = blockIdx.x * blockDim.x + threadIdx.x;
    int stride = gridDim.x * blockDim.x;
    for (int t = i; t < N_NODES; t += stride) cursor[t] = 0;
    for (int t = i; t < BB * N_NODES * DD; t += stride) {
        int b = t & 3; int d = (t >> 2) & 31; int n = t >> 7;
        float v = 0.f;
        if (n == h_index[b]) v = query_emb[r_index[b] * DD + d];
        x0a[t] = v;                              // [n][d][b]
        x0b[(size_t)n * 128 + b * 32 + d] = v;   // [n][b][d]
    }
}

__global__ void k_hist(const int* __restrict__ ei, int* __restrict__ cursor) {
    int e = blockIdx.x * blockDim.x + threadIdx.x;
    if (e < N_EDGES) atomicAdd(&cursor[ei[N_EDGES + e]], 1);
}

// per-block partial sums of deg histogram + log(deg)
__global__ void k_part(const int* __restrict__ cursor, int* __restrict__ bsum,
                       float* __restrict__ blog) {
    __shared__ int si[256];
    __shared__ float sf2[256];
    int tid = threadIdx.x;
    int i = blockIdx.x * 256 + tid;
    int v = (i < N_NODES) ? cursor[i] : 0;
    float lg = (i < N_NODES) ? logf((float)(v + 1)) : 0.f;
    si[tid] = v; sf2[tid] = lg;
    __syncthreads();
    for (int off = 128; off > 0; off >>= 1) {
        if (tid < off) { si[tid] += si[tid + off]; sf2[tid] += sf2[tid + off]; }
        __syncthreads();
    }
    if (tid == 0) { bsum[blockIdx.x] = si[0]; blog[blockIdx.x] = sf2[0]; }
}

// single small block: scan the 79 block sums; total log -> mean
__global__ void k_scan2(const int* __restrict__ bsum, const float* __restrict__ blog,
                        int* __restrict__ boff, float* __restrict__ meanw) {
    __shared__ int si[128];
    __shared__ float sf2[128];
    int t = threadIdx.x;
    int v = (t < NBLK) ? bsum[t] : 0;
    float lg = (t < NBLK) ? blog[t] : 0.f;
    si[t] = v; sf2[t] = lg;
    __syncthreads();
    for (int off = 1; off < 128; off <<= 1) {
        int tv = (t >= off) ? si[t - off] : 0;
        float tf = (t >= off) ? sf2[t - off] : 0.f;
        __syncthreads();
        si[t] += tv; sf2[t] += tf;
        __syncthreads();
    }
    if (t < NBLK) boff[t] = si[t] - v;                      // exclusive
    if (t == 127) meanw[0] = sf2[127] / (float)N_NODES;     // mean(log deg)
}

// per-block scan + global offset -> row_ptr/cursor; rdeg/scale/inv
__global__ void k_final(int* __restrict__ cursor, int* __restrict__ row_ptr,
                        const int* __restrict__ boff, const float* __restrict__ meanw,
                        float* __restrict__ rdeg, float* __restrict__ scale,
                        float* __restrict__ invs) {
    __shared__ int si[256];
    int tid = threadIdx.x;
    int i = blockIdx.x * 256 + tid;
    int v = (i < N_NODES) ? cursor[i] : 0;
    si[tid] = v;
    __syncthreads();
    for (int off = 1; off < 256; off <<= 1) {
        int tv = (tid >= off) ? si[tid - off] : 0;
        __syncthreads();
        si[tid] += tv;
        __syncthreads();
    }
    int rp = boff[blockIdx.x] + si[tid] - v;   // exclusive prefix
    if (i < N_NODES) {
        row_ptr[i] = rp;
        cursor[i] = rp;
        float dg = (float)(v + 1);
        float sc = logf(dg) / meanw[0];
        rdeg[i] = 1.f / dg;
        scale[i] = sc;
        invs[i] = 1.f / fmaxf(sc, 0.01f);
    }
    if (i == 0) row_ptr[N_NODES] = N_EDGES;
}

__global__ void k_scatter(const int* __restrict__ ei, const int* __restrict__ et,
                          int* __restrict__ cursor, int* __restrict__ es) {
    int e = blockIdx.x * blockDim.x + threadIdx.x;
    if (e < N_EDGES) {
        int dnode = ei[N_EDGES + e];
        int p = atomicAdd(&cursor[dnode], 1);
        es[p] = ei[e] | (et[e] << 16);
    }
}

// rel tables [l][ty][d][b] + prepped conv weights.
// pw layout per (l, og), og in [0,4) covering outputs o = og*8 .. og*8+7 (3328 floats):
//   r in [0,256):   x-part.  j = r>>3, o = og*8 + (r&7)
//   r in [256,3328): feats.  r2=r-256; jj=r2/96; rem=r2%96; pf=rem>>3 (= f*3+k);
//                   o = og*8 + (rem&7); col = 32 + (jj*4 + pf/3)*3 + pf%3
__global__ void k_prep_w(const float* __restrict__ query_emb, const int* __restrict__ r_index,
                         const float* __restrict__ rel_W, const float* __restrict__ rel_b,
                         const float* __restrict__ conv_W,
                         float* __restrict__ rel_all, float* __restrict__ pw) {
    int i = blockIdx.x * blockDim.x + threadIdx.x;
    const int NREL = LL * BB * RR * DD;
    if (i < NREL) {
        int d = i & 31;
        int ty = (i >> 5) % RR;
        int b = (i / (32 * RR)) & 3;
        int l = i / (32 * RR * BB);
        const float* q = query_emb + r_index[b] * DD;
        const float* w = rel_W + ((size_t)l * RR * DD + ty * DD + d) * DD;
        float acc = rel_b[l * RR * DD + ty * DD + d];
        #pragma unroll
        for (int k2 = 0; k2 < DD; ++k2) acc = fmaf(q[k2], w[k2], acc);
        rel_all[(((size_t)l * RR + ty) * DD + d) * BB + b] = acc;
    } else {
        int i2 = i - NREL;
        if (i2 >= LL * 4 * 3328) return;
        int r = i2 % 3328; int lg2 = i2 / 3328;
        int og = lg2 & 3, l = lg2 >> 2;
        int o, col;
        if (r < 256) { col = r >> 3; o = og * 8 + (r & 7); }
        else {
            int r2 = r - 256;
            int jj = r2 / 96, rem = r2 % 96;
            int pf = rem >> 3;
            o = og * 8 + (rem & 7);
            col = DD + (jj * 4 + pf / 3) * 3 + (pf % 3);
        }
        pw[i2] = conv_W[(size_t)(l * DD + o) * (13 * DD) + col];
    }
}

// ---------------- gather + PNA kernel (r11 config, unchanged) ----------------
// Wave per node (grid-stride). lane = d + 32*par; parity halves process alternate
// edges (4-deep unroll = 8 x-row dwordx4 loads in flight per wave); shfl_xor(32)
// combine. Reads layout A. Writes F transposed: Fq[(chunk*32+d)*64+task].
__launch_bounds__(256, 6)
__global__ void k_gather(const float* __restrict__ xinA, float4* __restrict__ Fq,
                         const int* __restrict__ row_ptr, const int* __restrict__ es,
                         const float* __restrict__ rel_l, const float* __restrict__ rdeg,
                         const int* __restrict__ h_index, const int* __restrict__ r_index,
                         const float* __restrict__ query_emb) {
    __shared__ __align__(16) float s_rel[RR * BB * DD];   // 18432 B, [ty][d][b]
    const int tid = threadIdx.x;
    {   // stage rel table once per block
        const float4* p4 = (const float4*)rel_l;
        float4* s4 = (float4*)s_rel;
        for (int i = tid; i < RR * BB * DD / 4; i += 256) s4[i] = p4[i];
    }
    const int lane = tid & 63;
    const int d = lane & 31;
    const int par = lane >> 5;
    int hb[4]; float qv[4];
    #pragma unroll
    for (int b = 0; b < 4; ++b) {
        hb[b] = h_index[b];
        qv[b] = query_emb[r_index[b] * DD + d];
    }
    __syncthreads();

    const int nwaves = gridDim.x * 4;
    for (int n = blockIdx.x * 4 + (tid >> 6); n < N_NODES; n += nwaves) {
        float sa[4], sq[4], mx[4], mn[4];
        #pragma unroll
        for (int b = 0; b < 4; ++b) {
            float bv = (n == hb[b]) ? qv[b] : 0.f;
            float bs = par ? 0.f : bv;        // count boundary message once in sum/sq
            sa[b] = bs; sq[b] = bs * bv; mx[b] = bv; mn[b] = bv;
        }
        auto proc = [&](int ee) {
            int pk = es[ee];
            float4 xv = *(const float4*)(xinA + ((size_t)(pk & 0xFFFF) * DD + d) * 4);
            float4 rv = *(const float4*)(s_rel + (((pk >> 16) * DD) + d) * 4);
            #pragma unroll
            for (int b = 0; b < 4; ++b) {
                float m = (&xv.x)[b] * (&rv.x)[b];
                sa[b] += m; sq[b] = fmaf(m, m, sq[b]);
                mx[b] = fmaxf(mx[b], m); mn[b] = fminf(mn[b], m);
            }
        };
        int e0 = row_ptr[n], e1 = row_ptr[n + 1];
        int e = e0 + par;                        // parity-strided: 2 edges per step
        for (; e + 6 < e1; e += 8) { proc(e); proc(e + 2); proc(e + 4); proc(e + 6); }
        for (; e < e1; e += 2) proc(e);
        #pragma unroll
        for (int b = 0; b < 4; ++b) {
            sa[b] += __shfl_xor(sa[b], 32);
            sq[b] += __shfl_xor(sq[b], 32);
            mx[b] = fmaxf(mx[b], __shfl_xor(mx[b], 32));
            mn[b] = fminf(mn[b], __shfl_xor(mn[b], 32));
        }
        float rd_ = rdeg[n];
        float mean[4], sd[4];
        #pragma unroll
        for (int b = 0; b < 4; ++b) {
            mean[b] = sa[b] * rd_;
            float sm = sq[b] * rd_;
            sd[b] = sqrtf(fmaxf(sm - mean[b] * mean[b], 1e-6f));
        }
        const int chunk = n >> 4, nl = n & 15;
        int tA = nl * 4 + par * 2;               // each half writes 2 tasks
        float4 fA, fB;
        fA.x = par ? mean[2] : mean[0]; fA.y = par ? mx[2] : mx[0];
        fA.z = par ? mn[2] : mn[0];     fA.w = par ? sd[2] : sd[0];
        fB.x = par ? mean[3] : mean[1]; fB.y = par ? mx[3] : mx[1];
        fB.z = par ? mn[3] : mn[1];     fB.w = par ? sd[3] : sd[1];
        Fq[(size_t)(chunk * 32 + d) * 64 + tA] = fA;
        Fq[(size_t)(chunk * 32 + d) * 64 + tA + 1] = fB;
    }
}

// ---------------- conv kernel ----------------
// One chunk per 256-thr block (grid = 1250, all co-resident). 4 waves = 4
// out-groups of 8 outputs; lane = task. Weights on the scalar path. r14 change:
// x-part reads layout B ([n][b][d]) as 8 contiguous float4 per lane (was 32
// stride-16B dwords touching ~8 L1 lines each -- ~4K cyc/chunk of line traffic);
// epilogue additionally writes layout B with 2 coalesced dwordx4 stores.
__launch_bounds__(256, 6)
__global__ void k_conv(const float* __restrict__ xinB, float* __restrict__ xoutA,
                       float* __restrict__ xoutB,
                       const float4* __restrict__ Fq, const float* __restrict__ pw_l,
                       const float* __restrict__ scale, const float* __restrict__ invs,
                       const float* __restrict__ conv_b_l) {
    const int tid = threadIdx.x;
    const int og = __builtin_amdgcn_readfirstlane(tid >> 6);   // 0..3, SGPR
    const int lane = tid & 63;
    const int chunk = blockIdx.x;
    const float* wxp = pw_l + og * 3328;      // x weights [32 j][8 o], uniform
    const float* wfp = wxp + 256;             // feat weights [32 jj][12 pf][8 o], uniform

    const int nl2 = lane >> 2, b2 = lane & 3;
    const int n = chunk * 16 + nl2;

    float y0[8], y1[8], y2[8];
    #pragma unroll
    for (int oo = 0; oo < 8; ++oo) {
        y0[oo] = conv_b_l[og * 8 + oo];
        y1[oo] = 0.f;
        y2[oo] = 0.f;
    }

    // ---- x part: 32 K-rows from layout B, 8 contiguous float4 per lane ----
    const float* xb = xinB + (size_t)n * 128 + b2 * 32;
    #pragma unroll 2
    for (int jg = 0; jg < 8; ++jg) {
        float4 c = *(const float4*)(xb + jg * 4);
        #pragma unroll
        for (int dj = 0; dj < 4; ++dj) {
            const float* wp = wxp + (jg * 4 + dj) * 8;
            float cv = (&c.x)[dj];
            #pragma unroll
            for (int oo = 0; oo < 8; ++oo) y0[oo] = fmaf(cv, wp[oo], y0[oo]);
        }
    }

    // ---- feats: 32 d-rows, f = mean/max/min/std, k-sets via y0/y1/y2 ----
    float4 fa = Fq[(size_t)(chunk * 32) * 64 + lane];
    #pragma unroll 1
    for (int jj = 0; jj < 32; ++jj) {
        float4 fb = Fq[(size_t)(chunk * 32 + jj + 1) * 64 + lane];  // slack row at end
        const float* wp = wfp + jj * 96;
        #pragma unroll
        for (int f = 0; f < 4; ++f) {
            float cv = (&fa.x)[f];
            const float* w8 = wp + f * 24;    // pf = f*3+k -> f*24 + k*8 + o
            #pragma unroll
            for (int oo = 0; oo < 8; ++oo) y0[oo] = fmaf(cv, w8[oo], y0[oo]);
            #pragma unroll
            for (int oo = 0; oo < 8; ++oo) y1[oo] = fmaf(cv, w8[8 + oo], y1[oo]);
            #pragma unroll
            for (int oo = 0; oo < 8; ++oo) y2[oo] = fmaf(cv, w8[16 + oo], y2[oo]);
        }
        fa = fb;
    }

    // ---- epilogue ----
    float scn = scale[n], ivn = invs[n];
    float v[8];
    #pragma unroll
    for (int oo = 0; oo < 8; ++oo)
        v[oo] = fmaxf(0.f, y0[oo] + scn * y1[oo] + ivn * y2[oo]);
    // layout A (for next gather): strided scalar stores
    float* xoA = xoutA + (size_t)n * 128 + b2;
    #pragma unroll
    for (int oo = 0; oo < 8; ++oo) xoA[(og * 8 + oo) * 4] = v[oo];
    // layout B (for next conv x-part + score): 2 coalesced dwordx4
    float* xoB = xoutB + (size_t)n * 128 + b2 * 32 + og * 8;
    *(float4*)&xoB[0] = make_float4(v[0], v[1], v[2], v[3]);
    *(float4*)&xoB[4] = make_float4(v[4], v[5], v[6], v[7]);
}

// ---------------- final scoring (reads layout B) ----------------
__global__ void k_score(const float* __restrict__ xLB, const float* __restrict__ query_emb,
                        const int* __restrict__ r_index, const int* __restrict__ t_index,
                        const float* __restrict__ W1, const float* __restrict__ b1,
                        const float* __restrict__ W2, const float* __restrict__ b2,
                        float* __restrict__ out) {
    int bi = blockIdx.x;            // 0..127
    int b = bi >> 5, kk = bi & 31;
    int j = threadIdx.x;            // 0..63
    __shared__ float sf[64];
    int t = t_index[b * KK + kk];
    float f = (j < DD) ? xLB[(size_t)t * 128 + b * 32 + j]
                       : query_emb[r_index[b] * DD + (j - DD)];
    sf[j] = f;
    __syncthreads();
    float acc = b1[j];
    #pragma unroll 8
    for (int i2 = 0; i2 < 64; ++i2) acc = fmaf(sf[i2], W1[j * 64 + i2], acc);
    float h = fmaxf(acc, 0.f);
    float prod = h * W2[j];
    #pragma unroll
    for (int off = 32; off > 0; off >>= 1) prod += __shfl_down(prod, off);
    if (j == 0) out[b * KK + kk] = prod + b2[0];
}

extern "C" void kernel_launch(void* const* d_in, const int* in_sizes, int n_in,
                              void* d_out, int out_size, void* d_ws, size_t ws_size,
                              hipStream_t stream) {
    const int* ei        = (const int*)d_in[0];
    const int* et        = (const int*)d_in[1];
    const int* h_index   = (const int*)d_in[2];
    const int* t_index   = (const int*)d_in[3];
    const int* r_index   = (const int*)d_in[4];
    const float* query_emb = (const float*)d_in[6];
    const float* rel_W   = (const float*)d_in[7];
    const float* rel_b   = (const float*)d_in[8];
    const float* conv_W  = (const float*)d_in[9];
    const float* conv_b  = (const float*)d_in[10];
    const float* W1      = (const float*)d_in[11];
    const float* b1      = (const float*)d_in[12];
    const float* W2      = (const float*)d_in[13];
    const float* b2      = (const float*)d_in[14];

    float* ws = (float*)d_ws;
    float* x0a     = ws + OFF_X0A;
    float* x1a     = ws + OFF_X1A;
    float* x0b     = ws + OFF_X0B;
    float* x1b     = ws + OFF_X1B;
    int*   row_ptr = (int*)(ws + OFF_RP);
    int*   cursor  = (int*)(ws + OFF_CUR);
    int*   es      = (int*)(ws + OFF_ES);
    float* rdeg    = ws + OFF_DEG;
    float* sc      = ws + OFF_SC;
    float* invs    = ws + OFF_INV;
    int*   bsum    = (int*)(ws + OFF_BS);
    float* blog    = ws + OFF_BL;
    int*   boff    = (int*)(ws + OFF_BO);
    float* meanw   = ws + OFF_MEAN;
    float* rel_all = ws + OFF_REL;
    float* pw      = ws + OFF_PW;
    float4* Fq     = (float4*)(ws + OFF_F);
    float* out     = (float*)d_out;

    // prep
    k_init<<<1024, 256, 0, stream>>>(h_index, r_index, query_emb, x0a, x0b, cursor);
    k_hist<<<(N_EDGES + 255) / 256, 256, 0, stream>>>(ei, cursor);
    k_part<<<NBLK, 256, 0, stream>>>(cursor, bsum, blog);
    k_scan2<<<1, 128, 0, stream>>>(bsum, blog, boff, meanw);
    k_final<<<NBLK, 256, 0, stream>>>(cursor, row_ptr, boff, meanw, rdeg, sc, invs);
    k_scatter<<<(N_EDGES + 255) / 256, 256, 0, stream>>>(ei, et, cursor, es);
    const int NPREP = LL * BB * RR * DD + LL * 4 * 3328;
    k_prep_w<<<(NPREP + 255) / 256, 256, 0, stream>>>(query_emb, r_index, rel_W, rel_b,
                                                      conv_W, rel_all, pw);

    // 4 BF layers, ping-pong (x0a,x0b)/(x1a,x1b)
    for (int l = 0; l < LL; ++l) {
        const float* xia = (l & 1) ? x1a : x0a;
        const float* xib = (l & 1) ? x1b : x0b;
        float* xoa = (l & 1) ? x0a : x1a;
        float* xob = (l & 1) ? x0b : x1b;
        k_gather<<<1536, 256, 0, stream>>>(xia, Fq, row_ptr, es,
                                           rel_all + (size_t)l * RR * BB * DD,
                                           rdeg, h_index, r_index, query_emb);
        k_conv<<<NCHUNKS, 256, 0, stream>>>(xib, xoa, xob, Fq,
                                            pw + (size_t)l * 4 * 3328,
                                            sc, invs, conv_b + l * DD);
    }

    float* xLb = (LL & 1) ? x1b : x0b;
    k_score<<<BB * KK, 64, 0, stream>>>(xLb, query_emb, r_index, t_index, W1, b1, W2, b2, out);
}

// Round 15
// 266.922 us; speedup vs baseline: 1.1633x; 1.0662x over previous
//
#include <hip/hip_runtime.h>
#include <hip/hip_bf16.h>

// NBFNet Bellman-Ford pass, MI355X. N=20000, E=200000, B=4, K=32, D=32, R=36, L=4.
// x layout: [n][d][b] (b innermost) -> gather reads one dwordx4 per edge per lane.
#define N_NODES 20000
#define N_EDGES 200000
#define BB 4
#define KK 32
#define DD 32
#define RR 36
#define LL 4
#define NCHUNKS (N_NODES / 16)   // 1250
#define NPAIRS (N_NODES / 2)     // 10000
#define NBLK 79                  // ceil(20000/256)

// ---------------- ws layout (element offsets, 4B units) ----------------
constexpr size_t OFF_X0   = 0;                                        // float[N*D*B], x[(n*32+d)*4+b]
constexpr size_t OFF_X1   = OFF_X0 + (size_t)BB * N_NODES * DD;
constexpr size_t OFF_RP   = OFF_X1 + (size_t)BB * N_NODES * DD;       // int[N+1]
constexpr size_t OFF_CUR  = OFF_RP + 20032;                           // int[N]
constexpr size_t OFF_ES   = OFF_CUR + N_NODES;                        // int[E] src | type<<16
constexpr size_t OFF_DEG  = OFF_ES + N_EDGES;                         // float[N] 1/deg
constexpr size_t OFF_SC   = OFF_DEG + N_NODES;                        // float[N] scale
constexpr size_t OFF_INV  = OFF_SC + N_NODES;                         // float[N] 1/max(scale,.01)
constexpr size_t OFF_BS   = OFF_INV + N_NODES;                        // int[128] block sums
constexpr size_t OFF_BL   = OFF_BS + 128;                             // float[128] block log sums
constexpr size_t OFF_BO   = OFF_BL + 128;                             // int[128] block offsets
constexpr size_t OFF_MEAN = OFF_BO + 128;                             // float[16]
constexpr size_t OFF_REL  = OFF_MEAN + 16;                            // float[L*R*D*B] [l][ty][d][b]
constexpr size_t OFF_PW   = OFF_REL + (size_t)LL * RR * BB * DD;      // float[L*4*3328]
constexpr size_t OFF_F    = OFF_PW + (size_t)LL * 4 * 3328;           // float4[(NCHUNKS*32+64)*64]
// Fq keeps 64 rows of slack: conv's ping-pong prefetch reads 1 row past each chunk.

// ---------------- prep kernels ----------------

__global__ void k_init(const int* __restrict__ h_index, const int* __restrict__ r_index,
                       const float* __restrict__ query_emb, float* __restrict__ x0,
                       int* __restrict__ cursor) {
    int i = blockIdx.x * blockDim.x + threadIdx.x;
    int stride = gridDim.x * blockDim.x;
    for (int t = i; t < N_NODES; t += stride) cursor[t] = 0;
    for (int t = i; t < BB * N_NODES * DD; t += stride) {
        int b = t & 3; int d = (t >> 2) & 31; int n = t >> 7;
        float v = 0.f;
        if (n == h_index[b]) v = query_emb[r_index[b] * DD + d];
        x0[t] = v;
    }
}

__global__ void k_hist(const int* __restrict__ ei, int* __restrict__ cursor) {
    int e = blockIdx.x * blockDim.x + threadIdx.x;
    if (e < N_EDGES) atomicAdd(&cursor[ei[N_EDGES + e]], 1);
}

// per-block partial sums of deg histogram + log(deg)
__global__ void k_part(const int* __restrict__ cursor, int* __restrict__ bsum,
                       float* __restrict__ blog) {
    __shared__ int si[256];
    __shared__ float sf2[256];
    int tid = threadIdx.x;
    int i = blockIdx.x * 256 + tid;
    int v = (i < N_NODES) ? cursor[i] : 0;
    float lg = (i < N_NODES) ? logf((float)(v + 1)) : 0.f;
    si[tid] = v; sf2[tid] = lg;
    __syncthreads();
    for (int off = 128; off > 0; off >>= 1) {
        if (tid < off) { si[tid] += si[tid + off]; sf2[tid] += sf2[tid + off]; }
        __syncthreads();
    }
    if (tid == 0) { bsum[blockIdx.x] = si[0]; blog[blockIdx.x] = sf2[0]; }
}

// single small block: scan the 79 block sums; total log -> mean
__global__ void k_scan2(const int* __restrict__ bsum, const float* __restrict__ blog,
                        int* __restrict__ boff, float* __restrict__ meanw) {
    __shared__ int si[128];
    __shared__ float sf2[128];
    int t = threadIdx.x;
    int v = (t < NBLK) ? bsum[t] : 0;
    float lg = (t < NBLK) ? blog[t] : 0.f;
    si[t] = v; sf2[t] = lg;
    __syncthreads();
    for (int off = 1; off < 128; off <<= 1) {
        int tv = (t >= off) ? si[t - off] : 0;
        float tf = (t >= off) ? sf2[t - off] : 0.f;
        __syncthreads();
        si[t] += tv; sf2[t] += tf;
        __syncthreads();
    }
    if (t < NBLK) boff[t] = si[t] - v;                      // exclusive
    if (t == 127) meanw[0] = sf2[127] / (float)N_NODES;     // mean(log deg)
}

// per-block scan + global offset -> row_ptr/cursor; rdeg/scale/inv
__global__ void k_final(int* __restrict__ cursor, int* __restrict__ row_ptr,
                        const int* __restrict__ boff, const float* __restrict__ meanw,
                        float* __restrict__ rdeg, float* __restrict__ scale,
                        float* __restrict__ invs) {
    __shared__ int si[256];
    int tid = threadIdx.x;
    int i = blockIdx.x * 256 + tid;
    int v = (i < N_NODES) ? cursor[i] : 0;
    si[tid] = v;
    __syncthreads();
    for (int off = 1; off < 256; off <<= 1) {
        int tv = (tid >= off) ? si[tid - off] : 0;
        __syncthreads();
        si[tid] += tv;
        __syncthreads();
    }
    int rp = boff[blockIdx.x] + si[tid] - v;   // exclusive prefix
    if (i < N_NODES) {
        row_ptr[i] = rp;
        cursor[i] = rp;
        float dg = (float)(v + 1);
        float sc = logf(dg) / meanw[0];
        rdeg[i] = 1.f / dg;
        scale[i] = sc;
        invs[i] = 1.f / fmaxf(sc, 0.01f);
    }
    if (i == 0) row_ptr[N_NODES] = N_EDGES;
}

__global__ void k_scatter(const int* __restrict__ ei, const int* __restrict__ et,
                          int* __restrict__ cursor, int* __restrict__ es) {
    int e = blockIdx.x * blockDim.x + threadIdx.x;
    if (e < N_EDGES) {
        int dnode = ei[N_EDGES + e];
        int p = atomicAdd(&cursor[dnode], 1);
        es[p] = ei[e] | (et[e] << 16);
    }
}

// rel tables [l][ty][d][b] + prepped conv weights.
// pw layout per (l, og), og in [0,4) covering outputs o = og*8 .. og*8+7 (3328 floats):
//   r in [0,256):   x-part.  j = r>>3, o = og*8 + (r&7)
//   r in [256,3328): feats.  r2=r-256; jj=r2/96; rem=r2%96; pf=rem>>3 (= f*3+k);
//                   o = og*8 + (rem&7); col = 32 + (jj*4 + pf/3)*3 + pf%3
__global__ void k_prep_w(const float* __restrict__ query_emb, const int* __restrict__ r_index,
                         const float* __restrict__ rel_W, const float* __restrict__ rel_b,
                         const float* __restrict__ conv_W,
                         float* __restrict__ rel_all, float* __restrict__ pw) {
    int i = blockIdx.x * blockDim.x + threadIdx.x;
    const int NREL = LL * BB * RR * DD;
    if (i < NREL) {
        int d = i & 31;
        int ty = (i >> 5) % RR;
        int b = (i / (32 * RR)) & 3;
        int l = i / (32 * RR * BB);
        const float* q = query_emb + r_index[b] * DD;
        const float* w = rel_W + ((size_t)l * RR * DD + ty * DD + d) * DD;
        float acc = rel_b[l * RR * DD + ty * DD + d];
        #pragma unroll
        for (int k2 = 0; k2 < DD; ++k2) acc = fmaf(q[k2], w[k2], acc);
        rel_all[(((size_t)l * RR + ty) * DD + d) * BB + b] = acc;
    } else {
        int i2 = i - NREL;
        if (i2 >= LL * 4 * 3328) return;
        int r = i2 % 3328; int lg2 = i2 / 3328;
        int og = lg2 & 3, l = lg2 >> 2;
        int o, col;
        if (r < 256) { col = r >> 3; o = og * 8 + (r & 7); }
        else {
            int r2 = r - 256;
            int jj = r2 / 96, rem = r2 % 96;
            int pf = rem >> 3;
            o = og * 8 + (rem & 7);
            col = DD + (jj * 4 + pf / 3) * 3 + (pf % 3);
        }
        pw[i2] = conv_W[(size_t)(l * DD + o) * (13 * DD) + col];
    }
}

// ---------------- gather + PNA kernel ----------------
// r15: wave per PAIR of consecutive nodes, two independent accumulator sets,
// interleaved 2x2 edge loop -> 4 independent load chains at degree >= 8 (the
// r11 4-deep unroll only filled at degree >= 16; mean degree is 10, so typical
// in-flight was 1-2 and L2/L3 latency was exposed). Single-node 4-deep drains
// handle imbalance tails. launch_bounds(256,5): ~102 VGPR cap for the 2x state.
__launch_bounds__(256, 5)
__global__ void k_gather(const float* __restrict__ xin, float4* __restrict__ Fq,
                         const int* __restrict__ row_ptr, const int* __restrict__ es,
                         const float* __restrict__ rel_l, const float* __restrict__ rdeg,
                         const int* __restrict__ h_index, const int* __restrict__ r_index,
                         const float* __restrict__ query_emb) {
    __shared__ __align__(16) float s_rel[RR * BB * DD];   // 18432 B, [ty][d][b]
    const int tid = threadIdx.x;
    {   // stage rel table once per block
        const float4* p4 = (const float4*)rel_l;
        float4* s4 = (float4*)s_rel;
        for (int i = tid; i < RR * BB * DD / 4; i += 256) s4[i] = p4[i];
    }
    const int lane = tid & 63;
    const int d = lane & 31;
    const int par = lane >> 5;
    int hb[4]; float qv[4];
    #pragma unroll
    for (int b = 0; b < 4; ++b) {
        hb[b] = h_index[b];
        qv[b] = query_emb[r_index[b] * DD + d];
    }
    __syncthreads();

    const int nwaves = gridDim.x * 4;
    for (int p = blockIdx.x * 4 + (tid >> 6); p < NPAIRS; p += nwaves) {
        const int n0 = 2 * p, n1 = 2 * p + 1;
        float sa0[4], sq0[4], mx0[4], mn0[4];
        float sa1[4], sq1[4], mx1[4], mn1[4];
        #pragma unroll
        for (int b = 0; b < 4; ++b) {
            float bv0 = (n0 == hb[b]) ? qv[b] : 0.f;
            float bs0 = par ? 0.f : bv0;      // count boundary message once in sum/sq
            sa0[b] = bs0; sq0[b] = bs0 * bv0; mx0[b] = bv0; mn0[b] = bv0;
            float bv1 = (n1 == hb[b]) ? qv[b] : 0.f;
            float bs1 = par ? 0.f : bv1;
            sa1[b] = bs1; sq1[b] = bs1 * bv1; mx1[b] = bv1; mn1[b] = bv1;
        }
        auto proc0 = [&](int ee) {
            int pk = es[ee];
            float4 xv = *(const float4*)(xin + ((size_t)(pk & 0xFFFF) * DD + d) * 4);
            float4 rv = *(const float4*)(s_rel + (((pk >> 16) * DD) + d) * 4);
            #pragma unroll
            for (int b = 0; b < 4; ++b) {
                float m = (&xv.x)[b] * (&rv.x)[b];
                sa0[b] += m; sq0[b] = fmaf(m, m, sq0[b]);
                mx0[b] = fmaxf(mx0[b], m); mn0[b] = fminf(mn0[b], m);
            }
        };
        auto proc1 = [&](int ee) {
            int pk = es[ee];
            float4 xv = *(const float4*)(xin + ((size_t)(pk & 0xFFFF) * DD + d) * 4);
            float4 rv = *(const float4*)(s_rel + (((pk >> 16) * DD) + d) * 4);
            #pragma unroll
            for (int b = 0; b < 4; ++b) {
                float m = (&xv.x)[b] * (&rv.x)[b];
                sa1[b] += m; sq1[b] = fmaf(m, m, sq1[b]);
                mx1[b] = fmaxf(mx1[b], m); mn1[b] = fminf(mn1[b], m);
            }
        };
        int ra = row_ptr[n0], rb = row_ptr[n1], rc = row_ptr[n1 + 1];
        int ea = ra + par, eb = rb + par;
        // interleaved 2x2: 4 independent chains while both nodes have edges
        for (; ea + 2 < rb && eb + 2 < rc; ea += 4, eb += 4) {
            proc0(ea); proc1(eb); proc0(ea + 2); proc1(eb + 2);
        }
        for (; ea < rb && eb < rc; ea += 2, eb += 2) { proc0(ea); proc1(eb); }
        // drain node 0 (4-deep)
        for (; ea + 6 < rb; ea += 8) { proc0(ea); proc0(ea + 2); proc0(ea + 4); proc0(ea + 6); }
        for (; ea < rb; ea += 2) proc0(ea);
        // drain node 1 (4-deep)
        for (; eb + 6 < rc; eb += 8) { proc1(eb); proc1(eb + 2); proc1(eb + 4); proc1(eb + 6); }
        for (; eb < rc; eb += 2) proc1(eb);

        #pragma unroll
        for (int b = 0; b < 4; ++b) {
            sa0[b] += __shfl_xor(sa0[b], 32);
            sq0[b] += __shfl_xor(sq0[b], 32);
            mx0[b] = fmaxf(mx0[b], __shfl_xor(mx0[b], 32));
            mn0[b] = fminf(mn0[b], __shfl_xor(mn0[b], 32));
            sa1[b] += __shfl_xor(sa1[b], 32);
            sq1[b] += __shfl_xor(sq1[b], 32);
            mx1[b] = fmaxf(mx1[b], __shfl_xor(mx1[b], 32));
            mn1[b] = fminf(mn1[b], __shfl_xor(mn1[b], 32));
        }
        float rd0 = rdeg[n0], rd1 = rdeg[n1];
        float mean0[4], sd0[4], mean1[4], sd1[4];
        #pragma unroll
        for (int b = 0; b < 4; ++b) {
            mean0[b] = sa0[b] * rd0;
            float sm0 = sq0[b] * rd0;
            sd0[b] = sqrtf(fmaxf(sm0 - mean0[b] * mean0[b], 1e-6f));
            mean1[b] = sa1[b] * rd1;
            float sm1 = sq1[b] * rd1;
            sd1[b] = sqrtf(fmaxf(sm1 - mean1[b] * mean1[b], 1e-6f));
        }
        {
            const int chunk = n0 >> 4, nl = n0 & 15;
            int tA = nl * 4 + par * 2;           // each half writes 2 tasks
            float4 fA, fB;
            fA.x = par ? mean0[2] : mean0[0]; fA.y = par ? mx0[2] : mx0[0];
            fA.z = par ? mn0[2] : mn0[0];     fA.w = par ? sd0[2] : sd0[0];
            fB.x = par ? mean0[3] : mean0[1]; fB.y = par ? mx0[3] : mx0[1];
            fB.z = par ? mn0[3] : mn0[1];     fB.w = par ? sd0[3] : sd0[1];
            Fq[(size_t)(chunk * 32 + d) * 64 + tA] = fA;
            Fq[(size_t)(chunk * 32 + d) * 64 + tA + 1] = fB;
        }
        {
            const int chunk = n1 >> 4, nl = n1 & 15;
            int tA = nl * 4 + par * 2;
            float4 fA, fB;
            fA.x = par ? mean1[2] : mean1[0]; fA.y = par ? mx1[2] : mx1[0];
            fA.z = par ? mn1[2] : mn1[0];     fA.w = par ? sd1[2] : sd1[0];
            fB.x = par ? mean1[3] : mean1[1]; fB.y = par ? mx1[3] : mx1[1];
            fB.z = par ? mn1[3] : mn1[1];     fB.w = par ? sd1[3] : sd1[1];
            Fq[(size_t)(chunk * 32 + d) * 64 + tA] = fA;
            Fq[(size_t)(chunk * 32 + d) * 64 + tA + 1] = fB;
        }
    }
}

// ---------------- conv kernel (r11 verbatim) ----------------
// One chunk per 256-thr block (grid = 1250, all co-resident). 4 waves = 4
// out-groups of 8 outputs; lane = task. Weights on the scalar path (uniform
// base + compile-time offsets -> s_load, K$/L2-hot). No LDS, no barriers.
__launch_bounds__(256, 6)
__global__ void k_conv(const float* __restrict__ xin, float* __restrict__ xout,
                       const float4* __restrict__ Fq, const float* __restrict__ pw_l,
                       const float* __restrict__ scale, const float* __restrict__ invs,
                       const float* __restrict__ conv_b_l) {
    const int tid = threadIdx.x;
    const int og = __builtin_amdgcn_readfirstlane(tid >> 6);   // 0..3, SGPR
    const int lane = tid & 63;
    const int chunk = blockIdx.x;
    const float* wxp = pw_l + og * 3328;      // x weights [32 j][8 o], uniform
    const float* wfp = wxp + 256;             // feat weights [32 jj][12 pf][8 o], uniform

    const int nl2 = lane >> 2, b2 = lane & 3;
    const int n = chunk * 16 + nl2;

    float y0[8], y1[8], y2[8];
    #pragma unroll
    for (int oo = 0; oo < 8; ++oo) {
        y0[oo] = conv_b_l[og * 8 + oo];
        y1[oo] = 0.f;
        y2[oo] = 0.f;
    }

    // ---- x part: 32 K-rows ([n][d][b] layout) ----
    const float* xb = xin + (size_t)n * 128 + b2;
    #pragma unroll 2
    for (int jg = 0; jg < 8; ++jg) {
        float cxv[4];
        #pragma unroll
        for (int dj = 0; dj < 4; ++dj) cxv[dj] = xb[(jg * 4 + dj) * 4];
        #pragma unroll
        for (int dj = 0; dj < 4; ++dj) {
            const float* wp = wxp + (jg * 4 + dj) * 8;
            #pragma unroll
            for (int oo = 0; oo < 8; ++oo) y0[oo] = fmaf(cxv[dj], wp[oo], y0[oo]);
        }
    }

    // ---- feats: 32 d-rows, f = mean/max/min/std, k-sets via y0/y1/y2 ----
    float4 fa = Fq[(size_t)(chunk * 32) * 64 + lane];
    #pragma unroll 1
    for (int jj = 0; jj < 32; ++jj) {
        float4 fb = Fq[(size_t)(chunk * 32 + jj + 1) * 64 + lane];  // slack row at end
        const float* wp = wfp + jj * 96;
        #pragma unroll
        for (int f = 0; f < 4; ++f) {
            float cv = (&fa.x)[f];
            const float* w8 = wp + f * 24;    // pf = f*3+k -> f*24 + k*8 + o
            #pragma unroll
            for (int oo = 0; oo < 8; ++oo) y0[oo] = fmaf(cv, w8[oo], y0[oo]);
            #pragma unroll
            for (int oo = 0; oo < 8; ++oo) y1[oo] = fmaf(cv, w8[8 + oo], y1[oo]);
            #pragma unroll
            for (int oo = 0; oo < 8; ++oo) y2[oo] = fmaf(cv, w8[16 + oo], y2[oo]);
        }
        fa = fb;
    }

    // ---- epilogue: out[n][o][b] scalar stores ----
    float scn = scale[n], ivn = invs[n];
    float* xo = xout + (size_t)n * 128 + b2;
    #pragma unroll
    for (int oo = 0; oo < 8; ++oo) {
        float v = fmaxf(0.f, y0[oo] + scn * y1[oo] + ivn * y2[oo]);
        xo[(og * 8 + oo) * 4] = v;
    }
}

// ---------------- final scoring ----------------
__global__ void k_score(const float* __restrict__ xL, const float* __restrict__ query_emb,
                        const int* __restrict__ r_index, const int* __restrict__ t_index,
                        const float* __restrict__ W1, const float* __restrict__ b1,
                        const float* __restrict__ W2, const float* __restrict__ b2,
                        float* __restrict__ out) {
    int bi = blockIdx.x;            // 0..127
    int b = bi >> 5, kk = bi & 31;
    int j = threadIdx.x;            // 0..63
    __shared__ float sf[64];
    int t = t_index[b * KK + kk];
    float f = (j < DD) ? xL[(size_t)t * 128 + j * 4 + b]
                       : query_emb[r_index[b] * DD + (j - DD)];
    sf[j] = f;
    __syncthreads();
    float acc = b1[j];
    #pragma unroll 8
    for (int i2 = 0; i2 < 64; ++i2) acc = fmaf(sf[i2], W1[j * 64 + i2], acc);
    float h = fmaxf(acc, 0.f);
    float prod = h * W2[j];
    #pragma unroll
    for (int off = 32; off > 0; off >>= 1) prod += __shfl_down(prod, off);
    if (j == 0) out[b * KK + kk] = prod + b2[0];
}

extern "C" void kernel_launch(void* const* d_in, const int* in_sizes, int n_in,
                              void* d_out, int out_size, void* d_ws, size_t ws_size,
                              hipStream_t stream) {
    const int* ei        = (const int*)d_in[0];
    const int* et        = (const int*)d_in[1];
    const int* h_index   = (const int*)d_in[2];
    const int* t_index   = (const int*)d_in[3];
    const int* r_index   = (const int*)d_in[4];
    const float* query_emb = (const float*)d_in[6];
    const float* rel_W   = (const float*)d_in[7];
    const float* rel_b   = (const float*)d_in[8];
    const float* conv_W  = (const float*)d_in[9];
    const float* conv_b  = (const float*)d_in[10];
    const float* W1      = (const float*)d_in[11];
    const float* b1      = (const float*)d_in[12];
    const float* W2      = (const float*)d_in[13];
    const float* b2      = (const float*)d_in[14];

    float* ws = (float*)d_ws;
    float* x0      = ws + OFF_X0;
    float* x1      = ws + OFF_X1;
    int*   row_ptr = (int*)(ws + OFF_RP);
    int*   cursor  = (int*)(ws + OFF_CUR);
    int*   es      = (int*)(ws + OFF_ES);
    float* rdeg    = ws + OFF_DEG;
    float* sc      = ws + OFF_SC;
    float* invs    = ws + OFF_INV;
    int*   bsum    = (int*)(ws + OFF_BS);
    float* blog    = ws + OFF_BL;
    int*   boff    = (int*)(ws + OFF_BO);
    float* meanw   = ws + OFF_MEAN;
    float* rel_all = ws + OFF_REL;
    float* pw      = ws + OFF_PW;
    float4* Fq     = (float4*)(ws + OFF_F);
    float* out     = (float*)d_out;

    // prep
    k_init<<<1024, 256, 0, stream>>>(h_index, r_index, query_emb, x0, cursor);
    k_hist<<<(N_EDGES + 255) / 256, 256, 0, stream>>>(ei, cursor);
    k_part<<<NBLK, 256, 0, stream>>>(cursor, bsum, blog);
    k_scan2<<<1, 128, 0, stream>>>(bsum, blog, boff, meanw);
    k_final<<<NBLK, 256, 0, stream>>>(cursor, row_ptr, boff, meanw, rdeg, sc, invs);
    k_scatter<<<(N_EDGES + 255) / 256, 256, 0, stream>>>(ei, et, cursor, es);
    const int NPREP = LL * BB * RR * DD + LL * 4 * 3328;
    k_prep_w<<<(NPREP + 255) / 256, 256, 0, stream>>>(query_emb, r_index, rel_W, rel_b,
                                                      conv_W, rel_all, pw);

    // 4 BF layers, ping-pong x0/x1
    for (int l = 0; l < LL; ++l) {
        const float* xi = (l & 1) ? x1 : x0;
        float* xo = (l & 1) ? x0 : x1;
        k_gather<<<1280, 256, 0, stream>>>(xi, Fq, row_ptr, es,
                                           rel_all + (size_t)l * RR * BB * DD,
                                           rdeg, h_index, r_index, query_emb);
        k_conv<<<NCHUNKS, 256, 0, stream>>>(xi, xo, Fq, pw + (size_t)l * 4 * 3328,
                                            sc, invs, conv_b + l * DD);
    }

    k_score<<<BB * KK, 64, 0, stream>>>(x0, query_emb, r_index, t_index, W1, b1, W2, b2, out);
}